// Round 6
// baseline (18410.999 us; speedup 1.0000x reference)
//
#include <hip/hip_runtime.h>

// Persistent 2-layer LSTM, plain launch (grid=256=#CUs, 1 block/CU => all
// resident). Split-fp16 MFMA GEMMs (A*B ~= Ahi*Bhi + Alo*Bhi + Ahi*Blo, fp32
// accum => ~22-bit mantissa), fp32 cell state / elementwise.
// WG (rb,cg): batch rows rb*64..+63, hidden units cg*8..+7 (32 gate cols).
// Cross-WG h exchange via VOLATILE (sc0 sc1) loads/stores => coherent at the
// Infinity Cache with NO buffer_wbl2/buffer_inv per tick (those were ~29us/tick
// in round 5). Store-based flag barrier, 4 independent 64-WG groups.

#define WGS    256
#define NTHR   256
#define TSTEPS 512
#define HDIM   512
#define BATCH  256
#define FUT    8
#define NCOL   (TSTEPS + FUT)
#define HPLANE (BATCH * HDIM)   // elements in one (hi or lo) h plane
#define FLAGSTRIDE 32           // u32s per flag line (128 B padding)

typedef _Float16 half_t;
typedef _Float16 f16x8 __attribute__((ext_vector_type(8)));
typedef float    f32x4 __attribute__((ext_vector_type(4)));

struct Params {
  const float* input_t;
  const float* W_ih1; const float* b_ih1; const float* W_hh1; const float* b_hh1;
  const float* W_ih2; const float* b_ih2; const float* W_hh2; const float* b_hh2;
  const float* W_lin; const float* b_lin;
  float* out;
  unsigned* flags;     // [WGS][FLAGSTRIDE]
  float* outfeed;
  half_t* h1buf;   // [2 pp][2 hi/lo][BATCH][HDIM]
  half_t* h2buf;   // [2 pp][2 hi/lo][BATCH][HDIM]
};

__device__ __forceinline__ float sigm(float x)   { return 1.0f / (1.0f + expf(-x)); }
__device__ __forceinline__ float tanh_f(float x) { return tanhf(x); }

// LLC-coherent (sc0 sc1) 16-B load — volatile => bypasses stale L1/L2.
__device__ __forceinline__ f16x8 vload8(const half_t* p) {
  return *(const volatile f16x8*)p;
}
// LLC-coherent packed store of 2 contiguous halfs (4 B, aligned).
__device__ __forceinline__ void vstore2(half_t* p, half_t a, half_t b) {
  union { half_t h[2]; unsigned u; } x;
  x.h[0] = a; x.h[1] = b;
  *(volatile unsigned*)p = x.u;
}

// fp32 row -> (hi, lo) fp16 fragments
__device__ __forceinline__ void load8_split(const float* p, f16x8& hi, f16x8& lo) {
  const float4 a = *(const float4*)p;
  const float4 b = *(const float4*)(p + 4);
  float v[8] = {a.x, a.y, a.z, a.w, b.x, b.y, b.z, b.w};
#pragma unroll
  for (int i = 0; i < 8; ++i) {
    const half_t h = (half_t)v[i];
    hi[i] = h;
    lo[i] = (half_t)(v[i] - (float)h);
  }
}

// Group barrier (64 WGs sharing rb). __syncthreads drains every wave's vmcnt
// (volatile stores then at LLC); thread 0 publishes flag; wave 0 polls the
// group's flags. No cache-maintenance fences: all cross-WG data moves via
// volatile (sc0 sc1) accesses, coherent at the LLC.
__device__ __forceinline__ void groupbar(unsigned* flags, int rb, int wg, unsigned target) {
  __syncthreads();   // all waves: s_waitcnt vmcnt(0) + s_barrier
  if (threadIdx.x == 0) {
    __hip_atomic_store(&flags[wg * FLAGSTRIDE], target,
                       __ATOMIC_RELAXED, __HIP_MEMORY_SCOPE_AGENT);
  }
  if (threadIdx.x < 64) {
    unsigned iters = 0;
    while (__hip_atomic_load(&flags[(rb * 64 + threadIdx.x) * FLAGSTRIDE],
                             __ATOMIC_RELAXED, __HIP_MEMORY_SCOPE_AGENT) < target) {
      __builtin_amdgcn_s_sleep(1);
      if (++iters > 5000000u) break;  // failsafe ~2 s, prevents suite hang
    }
  }
  __syncthreads();
}

__global__ void __launch_bounds__(NTHR, 1) lstm_fused(Params P) {
  const int tid  = threadIdx.x;
  const int wg   = blockIdx.x;
  const int cg   = wg & 63;    // unit group: hidden units cg*8 .. +7
  const int rb   = wg >> 6;    // row block: batch rows rb*64 .. +63
  const int wv   = tid >> 6;   // wave 0..3
  const int lane = tid & 63;
  const int rh   = wv >> 1;    // row half (32 rows)
  const int cc   = wv & 1;     // col half (16 of 32 gate cols)
  const int m    = lane & 15;
  const int quad = lane >> 4;

  __shared__ float g1s[64 * 33];          // L1 gate pre-acts [row][p]
  __shared__ float g2s[64 * 33];          // L2 gate pre-acts
  __shared__ f16x8 b1lo_s[2][16][64];     // W_hh1 lo fragments, per cc (32 KB)
  __shared__ float in_s[64];
  __shared__ float bias1_s[32];
  __shared__ float w1x_s[32];
  __shared__ float bias2_s[32];

  if (tid < 32) {
    const int gate = tid >> 3, ul = tid & 7;
    const int gc = gate * HDIM + cg * 8 + ul;
    bias1_s[tid] = P.b_ih1[gc] + P.b_hh1[gc];
    w1x_s[tid]   = P.W_ih1[gc];
    bias2_s[tid] = P.b_ih2[gc] + P.b_hh2[gc];
  }
  if (tid < 64) in_s[tid] = P.input_t[rb * 64 + tid];

  // Register-resident fp16 B fragments (hi for all, lo for W_ih2/W_hh2;
  // W_hh1 lo lives in LDS to stay under the VGPR spill threshold).
  // mfma_f32_16x16x32_f16 B layout: lane L holds B[k=(L>>4)*8+j][n=L&15].
  f16x8 B1h[16];    // W_hh1 hi
  f16x8 B2h[32];    // [0..15]=W_ih2 hi, [16..31]=W_hh2 hi
  f16x8 B2l[32];    // lo parts of W_ih2 / W_hh2
  {
    const int pcol = cc * 16 + m;
    const int gate = pcol >> 3, ul = pcol & 7;
    const int gc = gate * HDIM + cg * 8 + ul;
    const float* w1r  = P.W_hh1 + (size_t)gc * HDIM;
    const float* wi2r = P.W_ih2 + (size_t)gc * HDIM;
    const float* wh2r = P.W_hh2 + (size_t)gc * HDIM;
#pragma unroll
    for (int kk = 0; kk < 16; ++kk) {
      const int k0 = kk * 32 + quad * 8;
      f16x8 lo1;
      load8_split(w1r + k0, B1h[kk], lo1);
      load8_split(wi2r + k0, B2h[kk], B2l[kk]);
      load8_split(wh2r + k0, B2h[16 + kk], B2l[16 + kk]);
      if (wv < 2) b1lo_s[cc][kk][lane] = lo1;   // waves 0/1 cover cc 0/1
    }
  }
  __syncthreads();

  float c1[2] = {0.f, 0.f}, c2[2] = {0.f, 0.f};   // cell state (fp32, registers)
  const int eb  = tid >> 2;        // elementwise: batch row 0..63
  const int eu0 = (tid & 3) * 2;   // elementwise: first of 2 units

  // Output row: WG wg handles batch row wg (row wg is in its own rb group).
  auto outrow = [&](const half_t* h2p, int col) {
    if (tid < 64) {
      const f16x8 hv = vload8(h2p + (size_t)wg * HDIM + lane * 8);
      const f16x8 hl = vload8(h2p + HPLANE + (size_t)wg * HDIM + lane * 8);
      const float4 wa = *(const float4*)(P.W_lin + lane * 8);
      const float4 wb = *(const float4*)(P.W_lin + lane * 8 + 4);
      float s = ((float)hv[0] + (float)hl[0]) * wa.x + ((float)hv[1] + (float)hl[1]) * wa.y
              + ((float)hv[2] + (float)hl[2]) * wa.z + ((float)hv[3] + (float)hl[3]) * wa.w
              + ((float)hv[4] + (float)hl[4]) * wb.x + ((float)hv[5] + (float)hl[5]) * wb.y
              + ((float)hv[6] + (float)hl[6]) * wb.z + ((float)hv[7] + (float)hl[7]) * wb.w;
#pragma unroll
      for (int off = 32; off > 0; off >>= 1) s += __shfl_down(s, off);
      if (lane == 0) {
        s += P.b_lin[0];
        P.out[(size_t)wg * NCOL + col] = s;
        *(volatile float*)&P.outfeed[wg] = s;
      }
    }
  };

  auto tick = [&](bool doL1, bool doL2, bool doOUT, bool future, int outcol,
                  const half_t* h1rp, half_t* h1wp,
                  const half_t* h2rp, half_t* h2wp) {
    if (doOUT) outrow(h2rp, outcol);   // out[t-2] from h2[t-2]

    const f32x4 z4 = {0.f, 0.f, 0.f, 0.f};
    f32x4 acc1[2] = {z4, z4};
    f32x4 acc2[2] = {z4, z4};

    // A layout: lane L holds A[m=L&15][k=(L>>4)*8+j]
    const half_t* a1 = h1rp + (size_t)(rb * 64 + rh * 32 + m) * HDIM;
    const half_t* a2 = h2rp + (size_t)(rb * 64 + rh * 32 + m) * HDIM;
    const int koff = quad * 8;

#pragma unroll
    for (int kk = 0; kk < 16; ++kk) {   // k 0..511 : A = h1[t-1] (L1 & L2-x)
      if (doL1 | doL2) {
        const int o = kk * 32 + koff;
        const f16x8 a0h = vload8(a1 + o);
        const f16x8 a1h = vload8(a1 + 16 * HDIM + o);
        const f16x8 a0l = vload8(a1 + HPLANE + o);
        const f16x8 a1l = vload8(a1 + HPLANE + 16 * HDIM + o);
        if (doL1) {
          const f16x8 bl1 = b1lo_s[cc][kk][lane];
          acc1[0] = __builtin_amdgcn_mfma_f32_16x16x32_f16(a0h, B1h[kk], acc1[0], 0, 0, 0);
          acc1[1] = __builtin_amdgcn_mfma_f32_16x16x32_f16(a1h, B1h[kk], acc1[1], 0, 0, 0);
          acc1[0] = __builtin_amdgcn_mfma_f32_16x16x32_f16(a0l, B1h[kk], acc1[0], 0, 0, 0);
          acc1[1] = __builtin_amdgcn_mfma_f32_16x16x32_f16(a1l, B1h[kk], acc1[1], 0, 0, 0);
          acc1[0] = __builtin_amdgcn_mfma_f32_16x16x32_f16(a0h, bl1, acc1[0], 0, 0, 0);
          acc1[1] = __builtin_amdgcn_mfma_f32_16x16x32_f16(a1h, bl1, acc1[1], 0, 0, 0);
        }
        if (doL2) {
          acc2[0] = __builtin_amdgcn_mfma_f32_16x16x32_f16(a0h, B2h[kk], acc2[0], 0, 0, 0);
          acc2[1] = __builtin_amdgcn_mfma_f32_16x16x32_f16(a1h, B2h[kk], acc2[1], 0, 0, 0);
          acc2[0] = __builtin_amdgcn_mfma_f32_16x16x32_f16(a0l, B2h[kk], acc2[0], 0, 0, 0);
          acc2[1] = __builtin_amdgcn_mfma_f32_16x16x32_f16(a1l, B2h[kk], acc2[1], 0, 0, 0);
          acc2[0] = __builtin_amdgcn_mfma_f32_16x16x32_f16(a0h, B2l[kk], acc2[0], 0, 0, 0);
          acc2[1] = __builtin_amdgcn_mfma_f32_16x16x32_f16(a1h, B2l[kk], acc2[1], 0, 0, 0);
        }
      }
    }
#pragma unroll
    for (int kk = 0; kk < 16; ++kk) {   // k 512..1023 : A = h2[t-2] (L2 hidden)
      if (doL2) {
        const int o = kk * 32 + koff;
        const f16x8 a0h = vload8(a2 + o);
        const f16x8 a1h = vload8(a2 + 16 * HDIM + o);
        const f16x8 a0l = vload8(a2 + HPLANE + o);
        const f16x8 a1l = vload8(a2 + HPLANE + 16 * HDIM + o);
        acc2[0] = __builtin_amdgcn_mfma_f32_16x16x32_f16(a0h, B2h[16 + kk], acc2[0], 0, 0, 0);
        acc2[1] = __builtin_amdgcn_mfma_f32_16x16x32_f16(a1h, B2h[16 + kk], acc2[1], 0, 0, 0);
        acc2[0] = __builtin_amdgcn_mfma_f32_16x16x32_f16(a0l, B2h[16 + kk], acc2[0], 0, 0, 0);
        acc2[1] = __builtin_amdgcn_mfma_f32_16x16x32_f16(a1l, B2h[16 + kk], acc2[1], 0, 0, 0);
        acc2[0] = __builtin_amdgcn_mfma_f32_16x16x32_f16(a0h, B2l[16 + kk], acc2[0], 0, 0, 0);
        acc2[1] = __builtin_amdgcn_mfma_f32_16x16x32_f16(a1h, B2l[16 + kk], acc2[1], 0, 0, 0);
      }
    }

    // C/D layout: col = lane&15, row = (lane>>4)*4 + reg
    if (doL1) {
#pragma unroll
      for (int rt = 0; rt < 2; ++rt)
#pragma unroll
        for (int rg = 0; rg < 4; ++rg)
          g1s[(rh * 32 + rt * 16 + quad * 4 + rg) * 33 + cc * 16 + m] = acc1[rt][rg];
    }
    if (doL2) {
#pragma unroll
      for (int rt = 0; rt < 2; ++rt)
#pragma unroll
        for (int rg = 0; rg < 4; ++rg)
          g2s[(rh * 32 + rt * 16 + quad * 4 + rg) * 33 + cc * 16 + m] = acc2[rt][rg];
    }
    __syncthreads();

    // Elementwise: thread owns 2 (b,u) pairs; c-state stays in registers.
    // h written as packed (2-unit) volatile stores -> LLC-visible.
    float xb = 0.f;
    if (doL1) xb = future ? *(volatile const float*)&P.outfeed[rb * 64 + eb] : in_s[eb];
    if (doL1) {
      half_t hh[2], hl[2];
#pragma unroll
      for (int uu = 0; uu < 2; ++uu) {
        const int u = eu0 + uu;
        const float ai = g1s[eb * 33 + u]      + xb * w1x_s[u]      + bias1_s[u];
        const float af = g1s[eb * 33 + 8 + u]  + xb * w1x_s[8 + u]  + bias1_s[8 + u];
        const float ag = g1s[eb * 33 + 16 + u] + xb * w1x_s[16 + u] + bias1_s[16 + u];
        const float ao = g1s[eb * 33 + 24 + u] + xb * w1x_s[24 + u] + bias1_s[24 + u];
        const float ig = sigm(ai), fg = sigm(af), gg = tanh_f(ag), og = sigm(ao);
        const float c = fg * c1[uu] + ig * gg;
        c1[uu] = c;
        const float h = og * tanh_f(c);
        hh[uu] = (half_t)h;
        hl[uu] = (half_t)(h - (float)hh[uu]);
      }
      const size_t idx = (size_t)(rb * 64 + eb) * HDIM + cg * 8 + eu0;
      vstore2(h1wp + idx, hh[0], hh[1]);
      vstore2(h1wp + HPLANE + idx, hl[0], hl[1]);
    }
    if (doL2) {
      half_t hh[2], hl[2];
#pragma unroll
      for (int uu = 0; uu < 2; ++uu) {
        const int u = eu0 + uu;
        const float ai = g2s[eb * 33 + u]      + bias2_s[u];
        const float af = g2s[eb * 33 + 8 + u]  + bias2_s[8 + u];
        const float ag = g2s[eb * 33 + 16 + u] + bias2_s[16 + u];
        const float ao = g2s[eb * 33 + 24 + u] + bias2_s[24 + u];
        const float ig = sigm(ai), fg = sigm(af), gg = tanh_f(ag), og = sigm(ao);
        const float c = fg * c2[uu] + ig * gg;
        c2[uu] = c;
        const float h = og * tanh_f(c);
        hh[uu] = (half_t)h;
        hl[uu] = (half_t)(h - (float)hh[uu]);
      }
      const size_t idx = (size_t)(rb * 64 + eb) * HDIM + cg * 8 + eu0;
      vstore2(h2wp + idx, hh[0], hh[1]);
      vstore2(h2wp + HPLANE + idx, hl[0], hl[1]);
    }
  };

  half_t* h1b0 = P.h1buf;  half_t* h1b1 = P.h1buf + 2 * HPLANE;
  half_t* h2b0 = P.h2buf;  half_t* h2b1 = P.h2buf + 2 * HPLANE;

  unsigned bid = 0;
  // Main pipelined ticks: tick t = L1 step t, L2 step t-1, OUT step t-2.
  // h1[s] lives in h1buf[s&1]; h2[s] in h2buf[s&1]. Buffers pre-zeroed.
  for (int t = 0; t <= TSTEPS; ++t) {
    half_t* h1r = ((t + 1) & 1) ? h1b1 : h1b0;   // h1[t-1]
    half_t* h1w = (t & 1)       ? h1b1 : h1b0;   // h1[t]
    half_t* h2r = (t & 1)       ? h2b1 : h2b0;   // h2[t-2]
    half_t* h2w = ((t + 1) & 1) ? h2b1 : h2b0;   // h2[t-1]
    tick(t < TSTEPS, t >= 1, t >= 2, false, t - 2, h1r, h1w, h2r, h2w);
    groupbar(P.flags, rb, wg, ++bid);
  }
  // Autoregressive future steps: out feeds back => 3 phases each.
  for (int k = 0; k < FUT; ++k) {
    const int s = TSTEPS + k;
    const half_t* h2last = (((s - 1) & 1)) ? h2b1 : h2b0;  // h2[s-1]
    outrow(h2last, s - 1);
    groupbar(P.flags, rb, wg, ++bid);
    {  // L1 future step s (x = outfeed)
      half_t* h1r = (((s - 1) & 1)) ? h1b1 : h1b0;
      half_t* h1w = ((s & 1))       ? h1b1 : h1b0;
      tick(true, false, false, true, 0, h1r, h1w, h2b0, h2b0);
      groupbar(P.flags, rb, wg, ++bid);
    }
    {  // L2 future step s (x = h1[s], hidden = h2[s-1])
      half_t* h1r = ((s & 1))       ? h1b1 : h1b0;
      half_t* h2r = (((s - 1) & 1)) ? h2b1 : h2b0;
      half_t* h2w = ((s & 1))       ? h2b1 : h2b0;
      tick(false, true, false, false, 0, h1r, h1b0, h2r, h2w);
      groupbar(P.flags, rb, wg, ++bid);
    }
  }
  outrow((((TSTEPS + 7) & 1)) ? h2b1 : h2b0, TSTEPS + 7);
}

extern "C" void kernel_launch(void* const* d_in, const int* in_sizes, int n_in,
                              void* d_out, int out_size, void* d_ws, size_t ws_size,
                              hipStream_t stream) {
  Params P;
  P.input_t = (const float*)d_in[0];
  // d_in[1] = y : only its shape (T) matters; T hardcoded 512
  P.W_ih1 = (const float*)d_in[2];  P.b_ih1 = (const float*)d_in[3];
  P.W_hh1 = (const float*)d_in[4];  P.b_hh1 = (const float*)d_in[5];
  P.W_ih2 = (const float*)d_in[6];  P.b_ih2 = (const float*)d_in[7];
  P.W_hh2 = (const float*)d_in[8];  P.b_hh2 = (const float*)d_in[9];
  P.W_lin = (const float*)d_in[10]; P.b_lin = (const float*)d_in[11];
  P.out   = (float*)d_out;

  char* ws = (char*)d_ws;
  P.flags   = (unsigned*)(ws + 2048);                                 // 256*128 B = 32 KB
  P.outfeed = (float*)(ws + 256);
  P.h1buf   = (half_t*)(ws + 2048 + 32768);                           // [2][2][B][H]
  P.h2buf   = (half_t*)(ws + 2048 + 32768 + 4 * (size_t)HPLANE * sizeof(half_t));
  const size_t need = 2048 + 32768 + 8 * (size_t)HPLANE * sizeof(half_t);  // ~2.1 MB

  (void)hipMemsetAsync(d_ws, 0, need, stream);  // zero flags + outfeed + h buffers

  // PLAIN launch: grid == 256 CUs, 1 block/CU by resources => all resident.
  lstm_fused<<<dim3(WGS), dim3(NTHR), 0, stream>>>(P);
}

// Round 7
// 12015.858 us; speedup vs baseline: 1.5322x; 1.5322x over previous
//
#include <hip/hip_runtime.h>

// Persistent 2-layer LSTM, plain launch (grid=256=#CUs, 1 block/CU => all
// resident). Split-fp16 MFMA GEMMs (A*B ~= Ahi*Bhi + Alo*Bhi + Ahi*Blo, fp32
// accum => ~22-bit mantissa), fp32 cell state / elementwise.
// WG (rb,cg): batch rows rb*64..+63, hidden units cg*8..+7 (32 gate cols).
// Cross-WG h exchange: writes = volatile (sc0 sc1) stores; reads = BULK ASYNC
// global_load_lds with aux=sc0|sc1 (0x11) -> coherent at LLC, one latency per
// 129-KB staging phase instead of a 16-deep per-MFMA load chain (R6's bug).
// Store-based flag barrier, 4 independent 64-WG groups (group rb self-contained).

#define WGS    256
#define NTHR   256
#define TSTEPS 512
#define HDIM   512
#define BATCH  256
#define FUT    8
#define NCOL   (TSTEPS + FUT)
#define HPLANE (BATCH * HDIM)   // elements in one (hi or lo) h plane
#define FLAGSTRIDE 32           // u32s per flag line (128 B padding)
#define ROWB   1032             // staged LDS row pitch (1024 + 8 pad => bank spread)
#define LOOFF  (64 * ROWB)      // byte offset of lo-plane inside ldsA

typedef _Float16 half_t;
typedef _Float16 f16x8 __attribute__((ext_vector_type(8)));
typedef float    f32x4 __attribute__((ext_vector_type(4)));
typedef __attribute__((address_space(1))) const unsigned int gu32;
typedef __attribute__((address_space(3))) unsigned int su32;

struct Params {
  const float* input_t;
  const float* W_ih1; const float* b_ih1; const float* W_hh1; const float* b_hh1;
  const float* W_ih2; const float* b_ih2; const float* W_hh2; const float* b_hh2;
  const float* W_lin; const float* b_lin;
  float* out;
  unsigned* flags;     // [WGS][FLAGSTRIDE]
  float* outfeed;
  half_t* h1buf;   // [2 pp][2 hi/lo][BATCH][HDIM]
  half_t* h2buf;   // [2 pp][2 hi/lo][BATCH][HDIM]
};

__device__ __forceinline__ float sigm(float x)   { return 1.0f / (1.0f + expf(-x)); }
__device__ __forceinline__ float tanh_f(float x) { return tanhf(x); }

// LLC-coherent (sc0 sc1) 16-B load — volatile => bypasses stale L1/L2.
__device__ __forceinline__ f16x8 vload8(const half_t* p) {
  return *(const volatile f16x8*)p;
}
// LLC-coherent packed store of 2 contiguous halfs (4 B, aligned).
__device__ __forceinline__ void vstore2(half_t* p, half_t a, half_t b) {
  union { half_t h[2]; unsigned u; } x;
  x.h[0] = a; x.h[1] = b;
  *(volatile unsigned*)p = x.u;
}

// fp32 row -> (hi, lo) fp16 fragments
__device__ __forceinline__ void load8_split(const float* p, f16x8& hi, f16x8& lo) {
  const float4 a = *(const float4*)p;
  const float4 b = *(const float4*)(p + 4);
  float v[8] = {a.x, a.y, a.z, a.w, b.x, b.y, b.z, b.w};
#pragma unroll
  for (int i = 0; i < 8; ++i) {
    const half_t h = (half_t)v[i];
    hi[i] = h;
    lo[i] = (half_t)(v[i] - (float)h);
  }
}

// Group barrier (64 WGs sharing rb). __syncthreads drains vmcnt (volatile h
// stores then at LLC); thread 0 publishes flag; wave 0 polls group's flags.
__device__ __forceinline__ void groupbar(unsigned* flags, int rb, int wg, unsigned target) {
  __syncthreads();   // all waves: s_waitcnt vmcnt(0) + s_barrier
  if (threadIdx.x == 0) {
    __hip_atomic_store(&flags[wg * FLAGSTRIDE], target,
                       __ATOMIC_RELAXED, __HIP_MEMORY_SCOPE_AGENT);
  }
  if (threadIdx.x < 64) {
    unsigned iters = 0;
    while (__hip_atomic_load(&flags[(rb * 64 + threadIdx.x) * FLAGSTRIDE],
                             __ATOMIC_RELAXED, __HIP_MEMORY_SCOPE_AGENT) < target) {
      __builtin_amdgcn_s_sleep(1);
      if (++iters > 5000000u) break;  // failsafe, prevents suite hang
    }
  }
  __syncthreads();
}

__global__ void __launch_bounds__(NTHR, 1) lstm_fused(Params P) {
  const int tid  = threadIdx.x;
  const int wg   = blockIdx.x;
  const int cg   = wg & 63;    // unit group: hidden units cg*8 .. +7
  const int rb   = wg >> 6;    // row block: batch rows rb*64 .. +63
  const int wv   = tid >> 6;   // wave 0..3
  const int lane = tid & 63;
  const int rh   = wv >> 1;    // row half (32 rows)
  const int cc   = wv & 1;     // col half (16 of 32 gate cols)
  const int m    = lane & 15;
  const int quad = lane >> 4;

  __shared__ __align__(16) char ldsA[2 * LOOFF];   // staged A: hi rows + lo rows (129 KB)
  __shared__ float g1s[64 * 33];                   // L1 gate pre-acts [row][p]
  __shared__ float g2s[64 * 33];                   // L2 gate pre-acts
  __shared__ float in_s[64];
  __shared__ float bias1_s[32];
  __shared__ float w1x_s[32];
  __shared__ float bias2_s[32];

  if (tid < 32) {
    const int gate = tid >> 3, ul = tid & 7;
    const int gc = gate * HDIM + cg * 8 + ul;
    bias1_s[tid] = P.b_ih1[gc] + P.b_hh1[gc];
    w1x_s[tid]   = P.W_ih1[gc];
    bias2_s[tid] = P.b_ih2[gc] + P.b_hh2[gc];
  }
  if (tid < 64) in_s[tid] = P.input_t[rb * 64 + tid];

  // Register-resident fp16 B fragments (hi+lo for all three matrices).
  // mfma_f32_16x16x32_f16 B layout: lane L holds B[k=(L>>4)*8+j][n=L&15].
  f16x8 B1h[16], B1l[16];   // W_hh1
  f16x8 B2h[32], B2l[32];   // [0..15]=W_ih2, [16..31]=W_hh2
  {
    const int pcol = cc * 16 + m;
    const int gate = pcol >> 3, ul = pcol & 7;
    const int gc = gate * HDIM + cg * 8 + ul;
    const float* w1r  = P.W_hh1 + (size_t)gc * HDIM;
    const float* wi2r = P.W_ih2 + (size_t)gc * HDIM;
    const float* wh2r = P.W_hh2 + (size_t)gc * HDIM;
#pragma unroll
    for (int kk = 0; kk < 16; ++kk) {
      const int k0 = kk * 32 + quad * 8;
      load8_split(w1r + k0, B1h[kk], B1l[kk]);
      load8_split(wi2r + k0, B2h[kk], B2l[kk]);
      load8_split(wh2r + k0, B2h[16 + kk], B2l[16 + kk]);
    }
  }
  __syncthreads();

  float c1[2] = {0.f, 0.f}, c2[2] = {0.f, 0.f};   // cell state (fp32, registers)
  const int eb  = tid >> 2;        // elementwise: batch row 0..63
  const int eu0 = (tid & 3) * 2;   // elementwise: first of 2 units

  // Async-stage all 64 rows (hi+lo) of h-plane hp into ldsA. Per wave: 32
  // global_load_lds (aux=0x11 => sc0 sc1: read at LLC coherence point).
  auto stageA = [&](const half_t* hp) {
#pragma unroll
    for (int r = 0; r < 16; ++r) {
      const int row = wv * 16 + r;
      const half_t* ghi = hp + (size_t)(rb * 64 + row) * HDIM + lane * 8;
      const half_t* glo = ghi + HPLANE;
      __builtin_amdgcn_global_load_lds((gu32*)ghi, (su32*)(ldsA + row * ROWB), 16, 0, 0x11);
      __builtin_amdgcn_global_load_lds((gu32*)glo, (su32*)(ldsA + LOOFF + row * ROWB), 16, 0, 0x11);
    }
  };

  // Output row: WG wg handles batch row wg (row wg is in its own rb group).
  auto outrow = [&](const half_t* h2p, int col) {
    if (tid < 64) {
      const f16x8 hv = vload8(h2p + (size_t)wg * HDIM + lane * 8);
      const f16x8 hl = vload8(h2p + HPLANE + (size_t)wg * HDIM + lane * 8);
      const float4 wa = *(const float4*)(P.W_lin + lane * 8);
      const float4 wb = *(const float4*)(P.W_lin + lane * 8 + 4);
      float s = ((float)hv[0] + (float)hl[0]) * wa.x + ((float)hv[1] + (float)hl[1]) * wa.y
              + ((float)hv[2] + (float)hl[2]) * wa.z + ((float)hv[3] + (float)hl[3]) * wa.w
              + ((float)hv[4] + (float)hl[4]) * wb.x + ((float)hv[5] + (float)hl[5]) * wb.y
              + ((float)hv[6] + (float)hl[6]) * wb.z + ((float)hv[7] + (float)hl[7]) * wb.w;
#pragma unroll
      for (int off = 32; off > 0; off >>= 1) s += __shfl_down(s, off);
      if (lane == 0) {
        s += P.b_lin[0];
        P.out[(size_t)wg * NCOL + col] = s;
        *(volatile float*)&P.outfeed[wg] = s;
      }
    }
  };

  const int rowA = rh * 32 + m;          // first A row this lane reads
  const int cofs = quad * 16;            // byte offset within row chunk pair

  auto tick = [&](bool doL1, bool doL2, bool doOUT, bool future, int outcol,
                  const half_t* h1rp, half_t* h1wp,
                  const half_t* h2rp, half_t* h2wp) {
    if (doOUT) outrow(h2rp, outcol);   // out[t-2] from h2[t-2]

    const f32x4 z4 = {0.f, 0.f, 0.f, 0.f};
    f32x4 acc1[2] = {z4, z4};
    f32x4 acc2[2] = {z4, z4};

    // ---- Phase A: A = h1 (used by L1-hidden and L2-x GEMMs) ----
    if (doL1 | doL2) {
      stageA(h1rp);
      __syncthreads();   // vmcnt(0): staged data in LDS
      const char* pa = ldsA + rowA * ROWB + cofs;
      const char* pb = ldsA + (rowA + 16) * ROWB + cofs;
#pragma unroll
      for (int kk = 0; kk < 16; ++kk) {
        const int o = kk * 64;
        const f16x8 a0h = *(const f16x8*)(pa + o);
        const f16x8 a1h = *(const f16x8*)(pb + o);
        const f16x8 a0l = *(const f16x8*)(pa + LOOFF + o);
        const f16x8 a1l = *(const f16x8*)(pb + LOOFF + o);
        if (doL1) {
          acc1[0] = __builtin_amdgcn_mfma_f32_16x16x32_f16(a0h, B1h[kk], acc1[0], 0, 0, 0);
          acc1[1] = __builtin_amdgcn_mfma_f32_16x16x32_f16(a1h, B1h[kk], acc1[1], 0, 0, 0);
          acc1[0] = __builtin_amdgcn_mfma_f32_16x16x32_f16(a0l, B1h[kk], acc1[0], 0, 0, 0);
          acc1[1] = __builtin_amdgcn_mfma_f32_16x16x32_f16(a1l, B1h[kk], acc1[1], 0, 0, 0);
          acc1[0] = __builtin_amdgcn_mfma_f32_16x16x32_f16(a0h, B1l[kk], acc1[0], 0, 0, 0);
          acc1[1] = __builtin_amdgcn_mfma_f32_16x16x32_f16(a1h, B1l[kk], acc1[1], 0, 0, 0);
        }
        if (doL2) {
          acc2[0] = __builtin_amdgcn_mfma_f32_16x16x32_f16(a0h, B2h[kk], acc2[0], 0, 0, 0);
          acc2[1] = __builtin_amdgcn_mfma_f32_16x16x32_f16(a1h, B2h[kk], acc2[1], 0, 0, 0);
          acc2[0] = __builtin_amdgcn_mfma_f32_16x16x32_f16(a0l, B2h[kk], acc2[0], 0, 0, 0);
          acc2[1] = __builtin_amdgcn_mfma_f32_16x16x32_f16(a1l, B2h[kk], acc2[1], 0, 0, 0);
          acc2[0] = __builtin_amdgcn_mfma_f32_16x16x32_f16(a0h, B2l[kk], acc2[0], 0, 0, 0);
          acc2[1] = __builtin_amdgcn_mfma_f32_16x16x32_f16(a1h, B2l[kk], acc2[1], 0, 0, 0);
        }
      }
    }

    // ---- Phase B: A = h2 (L2-hidden GEMM), re-stage same LDS region ----
    if (doL2) {
      __syncthreads();   // all phase-A ds_reads done before overwrite
      stageA(h2rp);
      __syncthreads();
      const char* pa = ldsA + rowA * ROWB + cofs;
      const char* pb = ldsA + (rowA + 16) * ROWB + cofs;
#pragma unroll
      for (int kk = 0; kk < 16; ++kk) {
        const int o = kk * 64;
        const f16x8 a0h = *(const f16x8*)(pa + o);
        const f16x8 a1h = *(const f16x8*)(pb + o);
        const f16x8 a0l = *(const f16x8*)(pa + LOOFF + o);
        const f16x8 a1l = *(const f16x8*)(pb + LOOFF + o);
        acc2[0] = __builtin_amdgcn_mfma_f32_16x16x32_f16(a0h, B2h[16 + kk], acc2[0], 0, 0, 0);
        acc2[1] = __builtin_amdgcn_mfma_f32_16x16x32_f16(a1h, B2h[16 + kk], acc2[1], 0, 0, 0);
        acc2[0] = __builtin_amdgcn_mfma_f32_16x16x32_f16(a0l, B2h[16 + kk], acc2[0], 0, 0, 0);
        acc2[1] = __builtin_amdgcn_mfma_f32_16x16x32_f16(a1l, B2h[16 + kk], acc2[1], 0, 0, 0);
        acc2[0] = __builtin_amdgcn_mfma_f32_16x16x32_f16(a0h, B2l[16 + kk], acc2[0], 0, 0, 0);
        acc2[1] = __builtin_amdgcn_mfma_f32_16x16x32_f16(a1h, B2l[16 + kk], acc2[1], 0, 0, 0);
      }
    }

    // C/D layout: col = lane&15, row = (lane>>4)*4 + reg
    if (doL1) {
#pragma unroll
      for (int rt = 0; rt < 2; ++rt)
#pragma unroll
        for (int rg = 0; rg < 4; ++rg)
          g1s[(rh * 32 + rt * 16 + quad * 4 + rg) * 33 + cc * 16 + m] = acc1[rt][rg];
    }
    if (doL2) {
#pragma unroll
      for (int rt = 0; rt < 2; ++rt)
#pragma unroll
        for (int rg = 0; rg < 4; ++rg)
          g2s[(rh * 32 + rt * 16 + quad * 4 + rg) * 33 + cc * 16 + m] = acc2[rt][rg];
    }
    __syncthreads();

    // Elementwise: thread owns 2 (b,u) pairs; c-state stays in registers.
    // h written as packed (2-unit) volatile stores -> LLC-visible.
    float xb = 0.f;
    if (doL1) xb = future ? *(volatile const float*)&P.outfeed[rb * 64 + eb] : in_s[eb];
    if (doL1) {
      half_t hh[2], hl[2];
#pragma unroll
      for (int uu = 0; uu < 2; ++uu) {
        const int u = eu0 + uu;
        const float ai = g1s[eb * 33 + u]      + xb * w1x_s[u]      + bias1_s[u];
        const float af = g1s[eb * 33 + 8 + u]  + xb * w1x_s[8 + u]  + bias1_s[8 + u];
        const float ag = g1s[eb * 33 + 16 + u] + xb * w1x_s[16 + u] + bias1_s[16 + u];
        const float ao = g1s[eb * 33 + 24 + u] + xb * w1x_s[24 + u] + bias1_s[24 + u];
        const float ig = sigm(ai), fg = sigm(af), gg = tanh_f(ag), og = sigm(ao);
        const float c = fg * c1[uu] + ig * gg;
        c1[uu] = c;
        const float h = og * tanh_f(c);
        hh[uu] = (half_t)h;
        hl[uu] = (half_t)(h - (float)hh[uu]);
      }
      const size_t idx = (size_t)(rb * 64 + eb) * HDIM + cg * 8 + eu0;
      vstore2(h1wp + idx, hh[0], hh[1]);
      vstore2(h1wp + HPLANE + idx, hl[0], hl[1]);
    }
    if (doL2) {
      half_t hh[2], hl[2];
#pragma unroll
      for (int uu = 0; uu < 2; ++uu) {
        const int u = eu0 + uu;
        const float ai = g2s[eb * 33 + u]      + bias2_s[u];
        const float af = g2s[eb * 33 + 8 + u]  + bias2_s[8 + u];
        const float ag = g2s[eb * 33 + 16 + u] + bias2_s[16 + u];
        const float ao = g2s[eb * 33 + 24 + u] + bias2_s[24 + u];
        const float ig = sigm(ai), fg = sigm(af), gg = tanh_f(ag), og = sigm(ao);
        const float c = fg * c2[uu] + ig * gg;
        c2[uu] = c;
        const float h = og * tanh_f(c);
        hh[uu] = (half_t)h;
        hl[uu] = (half_t)(h - (float)hh[uu]);
      }
      const size_t idx = (size_t)(rb * 64 + eb) * HDIM + cg * 8 + eu0;
      vstore2(h2wp + idx, hh[0], hh[1]);
      vstore2(h2wp + HPLANE + idx, hl[0], hl[1]);
    }
  };

  half_t* h1b0 = P.h1buf;  half_t* h1b1 = P.h1buf + 2 * HPLANE;
  half_t* h2b0 = P.h2buf;  half_t* h2b1 = P.h2buf + 2 * HPLANE;

  unsigned bid = 0;
  // Main pipelined ticks: tick t = L1 step t, L2 step t-1, OUT step t-2.
  // h1[s] lives in h1buf[s&1]; h2[s] in h2buf[s&1]. Buffers pre-zeroed.
  for (int t = 0; t <= TSTEPS; ++t) {
    half_t* h1r = ((t + 1) & 1) ? h1b1 : h1b0;   // h1[t-1]
    half_t* h1w = (t & 1)       ? h1b1 : h1b0;   // h1[t]
    half_t* h2r = (t & 1)       ? h2b1 : h2b0;   // h2[t-2]
    half_t* h2w = ((t + 1) & 1) ? h2b1 : h2b0;   // h2[t-1]
    tick(t < TSTEPS, t >= 1, t >= 2, false, t - 2, h1r, h1w, h2r, h2w);
    groupbar(P.flags, rb, wg, ++bid);
  }
  // Autoregressive future steps: out feeds back => 3 phases each.
  for (int k = 0; k < FUT; ++k) {
    const int s = TSTEPS + k;
    const half_t* h2last = (((s - 1) & 1)) ? h2b1 : h2b0;  // h2[s-1]
    outrow(h2last, s - 1);
    groupbar(P.flags, rb, wg, ++bid);
    {  // L1 future step s (x = outfeed)
      half_t* h1r = (((s - 1) & 1)) ? h1b1 : h1b0;
      half_t* h1w = ((s & 1))       ? h1b1 : h1b0;
      tick(true, false, false, true, 0, h1r, h1w, h2b0, h2b0);
      groupbar(P.flags, rb, wg, ++bid);
    }
    {  // L2 future step s (x = h1[s], hidden = h2[s-1])
      half_t* h1r = ((s & 1))       ? h1b1 : h1b0;
      half_t* h2r = (((s - 1) & 1)) ? h2b1 : h2b0;
      half_t* h2w = ((s & 1))       ? h2b1 : h2b0;
      tick(false, true, false, false, 0, h1r, h1b0, h2r, h2w);
      groupbar(P.flags, rb, wg, ++bid);
    }
  }
  outrow((((TSTEPS + 7) & 1)) ? h2b1 : h2b0, TSTEPS + 7);
}

extern "C" void kernel_launch(void* const* d_in, const int* in_sizes, int n_in,
                              void* d_out, int out_size, void* d_ws, size_t ws_size,
                              hipStream_t stream) {
  Params P;
  P.input_t = (const float*)d_in[0];
  // d_in[1] = y : only its shape (T) matters; T hardcoded 512
  P.W_ih1 = (const float*)d_in[2];  P.b_ih1 = (const float*)d_in[3];
  P.W_hh1 = (const float*)d_in[4];  P.b_hh1 = (const float*)d_in[5];
  P.W_ih2 = (const float*)d_in[6];  P.b_ih2 = (const float*)d_in[7];
  P.W_hh2 = (const float*)d_in[8];  P.b_hh2 = (const float*)d_in[9];
  P.W_lin = (const float*)d_in[10]; P.b_lin = (const float*)d_in[11];
  P.out   = (float*)d_out;

  char* ws = (char*)d_ws;
  P.flags   = (unsigned*)(ws + 2048);                                 // 256*128 B = 32 KB
  P.outfeed = (float*)(ws + 256);
  P.h1buf   = (half_t*)(ws + 2048 + 32768);                           // [2][2][B][H]
  P.h2buf   = (half_t*)(ws + 2048 + 32768 + 4 * (size_t)HPLANE * sizeof(half_t));
  const size_t need = 2048 + 32768 + 8 * (size_t)HPLANE * sizeof(half_t);  // ~2.1 MB

  (void)hipMemsetAsync(d_ws, 0, need, stream);  // zero flags + outfeed + h buffers

  // PLAIN launch: grid == 256 CUs, 1 block/CU by resources => all resident.
  lstm_fused<<<dim3(WGS), dim3(NTHR), 0, stream>>>(P);
}

// Round 8
// 6465.299 us; speedup vs baseline: 2.8477x; 1.8585x over previous
//
#include <hip/hip_runtime.h>

// Persistent 2-layer LSTM, plain launch (grid=256=#CUs, 1 block/CU).
// Decomposition: 8 row-groups x 32 col-WGs. WG = 32 batch rows x 64 gate cols
// (16 hidden units). A-operand = fp16 hi only (B split hi+lo in registers =>
// error ~ A-quant only, ~1e-5). Staging: h1+h2 bulk async global_load_lds
// (aux sc0|sc1 => LLC-coherent) in ONE burst per tick; per-tick fabric
// traffic 16 MB (was 66 MB at C=64 with hi+lo). Store-based flag barrier per
// 32-WG group. Tick t = L1 step t + L2 step t-1 (pipelined), 1 barrier/tick.

#define WGS    256
#define NTHR   256
#define TSTEPS 512
#define HDIM   512
#define BATCH  256
#define FUT    8
#define NCOL   (TSTEPS + FUT)
#define HPLANE (BATCH * HDIM)   // one h plane (fp16 hi only)
#define FLAGSTRIDE 32           // u32s per flag line (128 B)
#define ROWB   1032             // LDS row pitch bytes (1024 + 8 pad)
#define GPITCH 68               // g-tile row pitch (floats)

typedef _Float16 half_t;
typedef _Float16 f16x8 __attribute__((ext_vector_type(8)));
typedef float    f32x4 __attribute__((ext_vector_type(4)));
typedef __attribute__((address_space(1))) const unsigned int gu32;
typedef __attribute__((address_space(3))) unsigned int su32;

struct Params {
  const float* input_t;
  const float* W_ih1; const float* b_ih1; const float* W_hh1; const float* b_hh1;
  const float* W_ih2; const float* b_ih2; const float* W_hh2; const float* b_hh2;
  const float* W_lin; const float* b_lin;
  float* out;
  unsigned* flags;     // [WGS][FLAGSTRIDE]
  float* outfeed;
  half_t* h1buf;   // [2 pp][BATCH][HDIM]
  half_t* h2buf;   // [2 pp][BATCH][HDIM]
};

__device__ __forceinline__ float sigm(float x)   { return 1.0f / (1.0f + expf(-x)); }
__device__ __forceinline__ float tanh_f(float x) { return tanhf(x); }

// LLC-coherent (sc0 sc1) 16-B load — volatile => bypasses stale L1/L2.
__device__ __forceinline__ f16x8 vload8(const half_t* p) {
  return *(const volatile f16x8*)p;
}
// LLC-coherent packed store of 2 contiguous halfs (4 B, aligned).
__device__ __forceinline__ void vstore2(half_t* p, half_t a, half_t b) {
  union { half_t h[2]; unsigned u; } x;
  x.h[0] = a; x.h[1] = b;
  *(volatile unsigned*)p = x.u;
}

// fp32 row -> (hi, lo) fp16 fragments
__device__ __forceinline__ void load8_split(const float* p, f16x8& hi, f16x8& lo) {
  const float4 a = *(const float4*)p;
  const float4 b = *(const float4*)(p + 4);
  float v[8] = {a.x, a.y, a.z, a.w, b.x, b.y, b.z, b.w};
#pragma unroll
  for (int i = 0; i < 8; ++i) {
    const half_t h = (half_t)v[i];
    hi[i] = h;
    lo[i] = (half_t)(v[i] - (float)h);
  }
}

// Group barrier (32 WGs sharing a row-group). Store own flag (parallel, no
// RMW); threads 0..31 poll the group's flags; volatile h stores are already
// at the LLC when __syncthreads' vmcnt(0) drain completes.
__device__ __forceinline__ void groupbar(unsigned* flags, int gbase, int wg, unsigned target) {
  __syncthreads();   // s_waitcnt vmcnt(0) + s_barrier
  if (threadIdx.x == 0) {
    __hip_atomic_store(&flags[wg * FLAGSTRIDE], target,
                       __ATOMIC_RELAXED, __HIP_MEMORY_SCOPE_AGENT);
  }
  if (threadIdx.x < 32) {
    unsigned iters = 0;
    while (__hip_atomic_load(&flags[(gbase + threadIdx.x) * FLAGSTRIDE],
                             __ATOMIC_RELAXED, __HIP_MEMORY_SCOPE_AGENT) < target) {
      __builtin_amdgcn_s_sleep(1);
      if (++iters > 5000000u) break;  // failsafe, prevents suite hang
    }
  }
  __syncthreads();
}

__global__ void __launch_bounds__(NTHR, 1) lstm_fused(Params P) {
  const int tid  = threadIdx.x;
  const int wg   = blockIdx.x;
  const int cg   = wg & 31;    // col group: hidden units cg*16 .. +15
  const int rb   = wg >> 5;    // row group: batch rows rb*32 .. +31
  const int wv   = tid >> 6;   // wave 0..3 == gate index (i,f,g,o)
  const int lane = tid & 63;
  const int m    = lane & 15;
  const int quad = lane >> 4;

  __shared__ __align__(16) char ldsA1[32 * ROWB];  // staged h1 rows (33 KB)
  __shared__ __align__(16) char ldsA2[32 * ROWB];  // staged h2 rows (33 KB)
  __shared__ float g1s[32 * GPITCH];               // L1 gate pre-acts [row][p]
  __shared__ float g2s[32 * GPITCH];               // L2 gate pre-acts
  __shared__ float in_s[32];
  __shared__ float bias1_s[64];
  __shared__ float w1x_s[64];
  __shared__ float bias2_s[64];

  if (tid < 64) {   // p = tid: gate = p>>4, ul = p&15
    const int gate = tid >> 4, ul = tid & 15;
    const int gc = gate * HDIM + cg * 16 + ul;
    bias1_s[tid] = P.b_ih1[gc] + P.b_hh1[gc];
    w1x_s[tid]   = P.W_ih1[gc];
    bias2_s[tid] = P.b_ih2[gc] + P.b_hh2[gc];
  }
  if (tid < 32) in_s[tid] = P.input_t[rb * 32 + tid];

  // Register-resident fp16 B fragments (hi+lo, all three matrices).
  // mfma_f32_16x16x32_f16 B layout: lane L holds B[k=(L>>4)*8+j][n=L&15].
  // Wave wv covers gate wv, cols n -> gate col p = wv*16 + n.
  f16x8 B1h[16], B1l[16];   // W_hh1
  f16x8 B2h[32], B2l[32];   // [0..15]=W_ih2, [16..31]=W_hh2
  {
    const int gc = wv * HDIM + cg * 16 + m;   // this lane's B column
    const float* w1r  = P.W_hh1 + (size_t)gc * HDIM;
    const float* wi2r = P.W_ih2 + (size_t)gc * HDIM;
    const float* wh2r = P.W_hh2 + (size_t)gc * HDIM;
#pragma unroll
    for (int kk = 0; kk < 16; ++kk) {
      const int k0 = kk * 32 + quad * 8;
      load8_split(w1r + k0, B1h[kk], B1l[kk]);
      load8_split(wi2r + k0, B2h[kk], B2l[kk]);
      load8_split(wh2r + k0, B2h[16 + kk], B2l[16 + kk]);
    }
  }
  __syncthreads();

  float c1[2] = {0.f, 0.f}, c2[2] = {0.f, 0.f};   // cell state (fp32, registers)
  const int eb  = tid >> 3;        // elementwise: batch row 0..31
  const int eu0 = (tid & 7) * 2;   // elementwise: first of 2 units (0..14)

  // Bulk async stage: 8 rows per wave per plane (1024 B per instruction).
  auto stage = [&](const half_t* hp, char* ldst) {
#pragma unroll
    for (int r = 0; r < 8; ++r) {
      const int row = wv * 8 + r;
      const half_t* g = hp + (size_t)(rb * 32 + row) * HDIM + lane * 8;
      __builtin_amdgcn_global_load_lds((gu32*)g, (su32*)(ldst + row * ROWB), 16, 0, 0x11);
    }
  };

  // Output row: WG wg handles batch row wg (row wg is inside its own group).
  auto outrow = [&](const half_t* h2p, int col) {
    if (tid < 64) {
      const f16x8 hv = vload8(h2p + (size_t)wg * HDIM + lane * 8);
      const float4 wa = *(const float4*)(P.W_lin + lane * 8);
      const float4 wb = *(const float4*)(P.W_lin + lane * 8 + 4);
      float s = (float)hv[0]*wa.x + (float)hv[1]*wa.y + (float)hv[2]*wa.z + (float)hv[3]*wa.w
              + (float)hv[4]*wb.x + (float)hv[5]*wb.y + (float)hv[6]*wb.z + (float)hv[7]*wb.w;
#pragma unroll
      for (int off = 32; off > 0; off >>= 1) s += __shfl_down(s, off);
      if (lane == 0) {
        s += P.b_lin[0];
        P.out[(size_t)wg * NCOL + col] = s;
        *(volatile float*)&P.outfeed[wg] = s;
      }
    }
  };

  auto tick = [&](bool doL1, bool doL2, bool doOUT, bool future, int outcol,
                  const half_t* h1rp, half_t* h1wp,
                  const half_t* h2rp, half_t* h2wp) {
    // Merged staging: both phases issued up front, one vmcnt(0)+barrier.
    if (doL1 | doL2) stage(h1rp, ldsA1);
    if (doL2)        stage(h2rp, ldsA2);

    if (doOUT) outrow(h2rp, outcol);   // overlaps with staging in flight

    const f32x4 z4 = {0.f, 0.f, 0.f, 0.f};
    f32x4 acc1[2] = {z4, z4};
    f32x4 acc2[2] = {z4, z4};

    __syncthreads();   // staged data resident in LDS

    // A layout: lane L holds A[m=L&15][k=(L>>4)*8+j]; row tile rt: rows rt*16+m.
    const char* a1p = ldsA1 + m * ROWB + quad * 16;
    const char* a2p = ldsA2 + m * ROWB + quad * 16;

    if (doL1 | doL2) {
#pragma unroll
      for (int kk = 0; kk < 16; ++kk) {   // Phase A: A = h1[t-1]
        const int o = kk * 64;
        const f16x8 a0 = *(const f16x8*)(a1p + o);
        const f16x8 a1 = *(const f16x8*)(a1p + 16 * ROWB + o);
        if (doL1) {
          acc1[0] = __builtin_amdgcn_mfma_f32_16x16x32_f16(a0, B1h[kk], acc1[0], 0, 0, 0);
          acc1[1] = __builtin_amdgcn_mfma_f32_16x16x32_f16(a1, B1h[kk], acc1[1], 0, 0, 0);
          acc1[0] = __builtin_amdgcn_mfma_f32_16x16x32_f16(a0, B1l[kk], acc1[0], 0, 0, 0);
          acc1[1] = __builtin_amdgcn_mfma_f32_16x16x32_f16(a1, B1l[kk], acc1[1], 0, 0, 0);
        }
        if (doL2) {
          acc2[0] = __builtin_amdgcn_mfma_f32_16x16x32_f16(a0, B2h[kk], acc2[0], 0, 0, 0);
          acc2[1] = __builtin_amdgcn_mfma_f32_16x16x32_f16(a1, B2h[kk], acc2[1], 0, 0, 0);
          acc2[0] = __builtin_amdgcn_mfma_f32_16x16x32_f16(a0, B2l[kk], acc2[0], 0, 0, 0);
          acc2[1] = __builtin_amdgcn_mfma_f32_16x16x32_f16(a1, B2l[kk], acc2[1], 0, 0, 0);
        }
      }
    }
    if (doL2) {
#pragma unroll
      for (int kk = 0; kk < 16; ++kk) {   // Phase B: A = h2[t-2]
        const int o = kk * 64;
        const f16x8 a0 = *(const f16x8*)(a2p + o);
        const f16x8 a1 = *(const f16x8*)(a2p + 16 * ROWB + o);
        acc2[0] = __builtin_amdgcn_mfma_f32_16x16x32_f16(a0, B2h[16 + kk], acc2[0], 0, 0, 0);
        acc2[1] = __builtin_amdgcn_mfma_f32_16x16x32_f16(a1, B2h[16 + kk], acc2[1], 0, 0, 0);
        acc2[0] = __builtin_amdgcn_mfma_f32_16x16x32_f16(a0, B2l[16 + kk], acc2[0], 0, 0, 0);
        acc2[1] = __builtin_amdgcn_mfma_f32_16x16x32_f16(a1, B2l[16 + kk], acc2[1], 0, 0, 0);
      }
    }

    // C/D layout: col = lane&15 (tile col), row = rt*16 + quad*4 + reg.
    if (doL1) {
#pragma unroll
      for (int rt = 0; rt < 2; ++rt)
#pragma unroll
        for (int rg = 0; rg < 4; ++rg)
          g1s[(rt * 16 + quad * 4 + rg) * GPITCH + wv * 16 + m] = acc1[rt][rg];
    }
    if (doL2) {
#pragma unroll
      for (int rt = 0; rt < 2; ++rt)
#pragma unroll
        for (int rg = 0; rg < 4; ++rg)
          g2s[(rt * 16 + quad * 4 + rg) * GPITCH + wv * 16 + m] = acc2[rt][rg];
    }
    __syncthreads();

    // Elementwise: thread owns 2 (b,u) pairs; c-state stays in registers.
    float xb = 0.f;
    if (doL1) xb = future ? *(volatile const float*)&P.outfeed[rb * 32 + eb] : in_s[eb];
    if (doL1) {
      half_t hh[2];
#pragma unroll
      for (int uu = 0; uu < 2; ++uu) {
        const int u = eu0 + uu;
        const float ai = g1s[eb * GPITCH + u]      + xb * w1x_s[u]      + bias1_s[u];
        const float af = g1s[eb * GPITCH + 16 + u] + xb * w1x_s[16 + u] + bias1_s[16 + u];
        const float ag = g1s[eb * GPITCH + 32 + u] + xb * w1x_s[32 + u] + bias1_s[32 + u];
        const float ao = g1s[eb * GPITCH + 48 + u] + xb * w1x_s[48 + u] + bias1_s[48 + u];
        const float ig = sigm(ai), fg = sigm(af), gg = tanh_f(ag), og = sigm(ao);
        const float c = fg * c1[uu] + ig * gg;
        c1[uu] = c;
        hh[uu] = (half_t)(og * tanh_f(c));
      }
      vstore2(h1wp + (size_t)(rb * 32 + eb) * HDIM + cg * 16 + eu0, hh[0], hh[1]);
    }
    if (doL2) {
      half_t hh[2];
#pragma unroll
      for (int uu = 0; uu < 2; ++uu) {
        const int u = eu0 + uu;
        const float ai = g2s[eb * GPITCH + u]      + bias2_s[u];
        const float af = g2s[eb * GPITCH + 16 + u] + bias2_s[16 + u];
        const float ag = g2s[eb * GPITCH + 32 + u] + bias2_s[32 + u];
        const float ao = g2s[eb * GPITCH + 48 + u] + bias2_s[48 + u];
        const float ig = sigm(ai), fg = sigm(af), gg = tanh_f(ag), og = sigm(ao);
        const float c = fg * c2[uu] + ig * gg;
        c2[uu] = c;
        hh[uu] = (half_t)(og * tanh_f(c));
      }
      vstore2(h2wp + (size_t)(rb * 32 + eb) * HDIM + cg * 16 + eu0, hh[0], hh[1]);
    }
  };

  half_t* h1b0 = P.h1buf;  half_t* h1b1 = P.h1buf + HPLANE;
  half_t* h2b0 = P.h2buf;  half_t* h2b1 = P.h2buf + HPLANE;
  const int gbase = wg & ~31;

  unsigned bid = 0;
  // Main pipelined ticks: tick t = L1 step t, L2 step t-1, OUT step t-2.
  for (int t = 0; t <= TSTEPS; ++t) {
    half_t* h1r = ((t + 1) & 1) ? h1b1 : h1b0;   // h1[t-1]
    half_t* h1w = (t & 1)       ? h1b1 : h1b0;   // h1[t]
    half_t* h2r = (t & 1)       ? h2b1 : h2b0;   // h2[t-2]
    half_t* h2w = ((t + 1) & 1) ? h2b1 : h2b0;   // h2[t-1]
    tick(t < TSTEPS, t >= 1, t >= 2, false, t - 2, h1r, h1w, h2r, h2w);
    groupbar(P.flags, gbase, wg, ++bid);
  }
  // Autoregressive future steps: out feeds back => 3 phases each.
  for (int k = 0; k < FUT; ++k) {
    const int s = TSTEPS + k;
    const half_t* h2last = (((s - 1) & 1)) ? h2b1 : h2b0;  // h2[s-1]
    outrow(h2last, s - 1);
    groupbar(P.flags, gbase, wg, ++bid);
    {  // L1 future step s (x = outfeed)
      half_t* h1r = (((s - 1) & 1)) ? h1b1 : h1b0;
      half_t* h1w = ((s & 1))       ? h1b1 : h1b0;
      tick(true, false, false, true, 0, h1r, h1w, h2b0, h2b0);
      groupbar(P.flags, gbase, wg, ++bid);
    }
    {  // L2 future step s (x = h1[s], hidden = h2[s-1])
      half_t* h1r = ((s & 1))       ? h1b1 : h1b0;
      half_t* h2r = (((s - 1) & 1)) ? h2b1 : h2b0;
      half_t* h2w = ((s & 1))       ? h2b1 : h2b0;
      tick(false, true, false, false, 0, h1r, h1b0, h2r, h2w);
      groupbar(P.flags, gbase, wg, ++bid);
    }
  }
  outrow((((TSTEPS + 7) & 1)) ? h2b1 : h2b0, TSTEPS + 7);
}

extern "C" void kernel_launch(void* const* d_in, const int* in_sizes, int n_in,
                              void* d_out, int out_size, void* d_ws, size_t ws_size,
                              hipStream_t stream) {
  Params P;
  P.input_t = (const float*)d_in[0];
  // d_in[1] = y : only its shape (T) matters; T hardcoded 512
  P.W_ih1 = (const float*)d_in[2];  P.b_ih1 = (const float*)d_in[3];
  P.W_hh1 = (const float*)d_in[4];  P.b_hh1 = (const float*)d_in[5];
  P.W_ih2 = (const float*)d_in[6];  P.b_ih2 = (const float*)d_in[7];
  P.W_hh2 = (const float*)d_in[8];  P.b_hh2 = (const float*)d_in[9];
  P.W_lin = (const float*)d_in[10]; P.b_lin = (const float*)d_in[11];
  P.out   = (float*)d_out;

  char* ws = (char*)d_ws;
  P.outfeed = (float*)(ws + 256);
  P.flags   = (unsigned*)(ws + 2048);                                 // 32 KB
  P.h1buf   = (half_t*)(ws + 2048 + 32768);                           // [2][B][H] = 512 KB
  P.h2buf   = (half_t*)(ws + 2048 + 32768 + 2 * (size_t)HPLANE * sizeof(half_t));
  const size_t need = 2048 + 32768 + 4 * (size_t)HPLANE * sizeof(half_t);  // ~1.1 MB

  (void)hipMemsetAsync(d_ws, 0, need, stream);  // zero flags + outfeed + h buffers

  // PLAIN launch: grid == 256 CUs, 1 block/CU by resources => all resident.
  lstm_fused<<<dim3(WGS), dim3(NTHR), 0, stream>>>(P);
}